// Round 4
// baseline (2841.164 us; speedup 1.0000x reference)
//
#include <hip/hip_runtime.h>
#include <hip/hip_bf16.h>

// ---------------------------------------------------------------------------
// XCD-local persistent LSTM, round 4 = proven round-2 skeleton (2812us) + ONE
// change: remote (IC) h publish moved off the self waves via an LDS relay.
//  - Phase 2 writes packed h to hpk[512] (LDS); after barrier 2, waves 0-3
//    issue the sc0 sc1 stores.  Self waves carry ZERO IC ops, so their
//    INV()/atom_rd vmcnt(0) at the head of the recurrence path drains only a
//    ~200cy L2 ack instead of a ~1us IC store.
//  - Publishing waves do NOT drain the stH2; it is the oldest vmem op at the
//    next step's first WAIT4(4)/WAIT8(8) and retires there, merged into load
//    latency (counts re-verified with the 1 carried store on every path).
//    Each wave retires it before barrier 1, so the round-2 claim
//    "fl_glob=t => slab t-1 sealed at barrier 1" stays valid.
//  - atom_add1 (local arrival) issued immediately after barrier 2, before the
//    IC publish, so the 32-block detect latency isn't queued behind it.
//  - Everything else identical to round 2 (proven): L2-atomic local flags,
//    stS(WT)+INV+plain-load data path, fbs/fas IC-flag caches, s_bgo funnel,
//    big-ring plain loads, capped waits (failures = slow-pass, never hang).
//  - Round-3 lesson: persistent reg staging pushed VGPR past the cliff;
//    spills add scratch ops to vmcnt and silently break hand-counted waits.
//    This round keeps round-2's ~120-VGPR footprint (relay is LDS).
// ---------------------------------------------------------------------------

#define BB 64
#define TT 512
#define DD 256
#define HH 512
#define GG 2048
#define SS (BB * HH)          // shorts per h slab (64 KB)
#define NBLK 256
#define NTHR 512
#define RL 8                  // local ring slots (L2-resident)
#define KPAD 1032
#define ZPAD 70
#define POLL_CAP 20000
#define SPIN_CAP (1 << 20)

using short8 = __attribute__((ext_vector_type(8))) short;
using f32x4  = __attribute__((ext_vector_type(4))) float;
using f4     = f32x4;
using u32x2  = __attribute__((ext_vector_type(2))) unsigned;

__device__ unsigned long long g_word = 0;
__device__ unsigned g_cnt[8] = {};

__device__ __forceinline__ short f2bf(float f) {
  unsigned u = __builtin_bit_cast(unsigned, f);
  u = (u + 0x7fffu + ((u >> 16) & 1u)) >> 16;   // RNE
  return (short)u;
}
__device__ __forceinline__ float sigm(float x)  { return 1.f / (1.f + __expf(-x)); }
__device__ __forceinline__ float tanh_(float x) { return 2.f / (1.f + __expf(-2.f * x)) - 1.f; }

__device__ __forceinline__ short8 pack8(const f4& lo, const f4& hi) {
  return (short8){f2bf(lo[0]), f2bf(lo[1]), f2bf(lo[2]), f2bf(lo[3]),
                  f2bf(hi[0]), f2bf(hi[1]), f2bf(hi[2]), f2bf(hi[3])};
}

// device-coherent (IC) stores -- cross-XCD protocol (proven)
__device__ __forceinline__ void stH(void* p, unsigned v) {
  asm volatile("global_store_dword %0, %1, off sc0 sc1" :: "v"(p), "v"(v) : "memory");
}
__device__ __forceinline__ void stH2(void* p, u32x2 v) {
  asm volatile("global_store_dwordx2 %0, %1, off sc0 sc1" :: "v"(p), "v"(v) : "memory");
}
// write-through store -- lands in the XCD L2 (proven round 2)
__device__ __forceinline__ void stS(void* p, unsigned v) {
  asm volatile("global_store_dword %0, %1, off sc0" :: "v"(p), "v"(v) : "memory");
}
// device-coherent poll load (IC)
__device__ __forceinline__ int ld_icc(const int* p) {
  int v;
  asm volatile("global_load_dword %0, %1, off sc0 sc1\n\ts_waitcnt vmcnt(0)"
               : "=v"(v) : "v"(p) : "memory");
  return v;
}
// L2 atomic read (return-old of +0) -- executes in L2, L1-immune (proven)
__device__ __forceinline__ unsigned atom_rd(unsigned* p) {
  unsigned old, zero = 0;
  asm volatile("global_atomic_add %0, %1, %2, off sc0\n\ts_waitcnt vmcnt(0)"
               : "=v"(old) : "v"(p), "v"(zero) : "memory");
  return old;
}
// L2 atomic add (fire-and-forget)
__device__ __forceinline__ void atom_add1(unsigned* p) {
  unsigned one = 1;
  asm volatile("global_atomic_add %0, %1, off" :: "v"(p), "v"(one) : "memory");
}
// L1 invalidate (acquire) -- proven round 2
#define INV() asm volatile("buffer_inv sc0\n\ts_waitcnt vmcnt(0)" ::: "memory")

// A loads: 4 M-tiles from one per-lane pointer (+512B per tile)
#define ISSUE4_A0(A, P)                                                        \
  asm volatile("global_load_dwordx4 %0, %4, off\n\t"                           \
               "global_load_dwordx4 %1, %4, off offset:512\n\t"                \
               "global_load_dwordx4 %2, %4, off offset:1024\n\t"               \
               "global_load_dwordx4 %3, %4, off offset:1536"                   \
               : "=&v"(A[0]), "=&v"(A[1]), "=&v"(A[2]), "=&v"(A[3]) : "v"(P))
#define ISSUE4_AH(A, P)                                                        \
  asm volatile("global_load_dwordx4 %0, %4, off sc0 sc1\n\t"                   \
               "global_load_dwordx4 %1, %4, off offset:512 sc0 sc1\n\t"        \
               "global_load_dwordx4 %2, %4, off offset:1024 sc0 sc1\n\t"       \
               "global_load_dwordx4 %3, %4, off offset:1536 sc0 sc1"           \
               : "=&v"(A[0]), "=&v"(A[1]), "=&v"(A[2]), "=&v"(A[3]) : "v"(P))

#define ISSUE_X(X, O0, O1, P)                                                    \
  asm volatile("global_load_dwordx4 %0, %8, off offset:" #O0 "\n\t"              \
               "global_load_dwordx4 %1, %8, off offset:" #O1 "\n\t"              \
               "global_load_dwordx4 %2, %9, off offset:" #O0 "\n\t"              \
               "global_load_dwordx4 %3, %9, off offset:" #O1 "\n\t"              \
               "global_load_dwordx4 %4, %10, off offset:" #O0 "\n\t"             \
               "global_load_dwordx4 %5, %10, off offset:" #O1 "\n\t"             \
               "global_load_dwordx4 %6, %11, off offset:" #O0 "\n\t"             \
               "global_load_dwordx4 %7, %11, off offset:" #O1                    \
               : "=&v"(X[0]), "=&v"(X[1]), "=&v"(X[2]), "=&v"(X[3]),             \
                 "=&v"(X[4]), "=&v"(X[5]), "=&v"(X[6]), "=&v"(X[7])              \
               : "v"(P[0]), "v"(P[1]), "v"(P[2]), "v"(P[3]))

#define WAIT4(N, A)                                                              \
  asm volatile("s_waitcnt vmcnt(" #N ")"                                         \
               : "+v"(A[0]), "+v"(A[1]), "+v"(A[2]), "+v"(A[3]))
#define WAIT8(N, X)                                                              \
  asm volatile("s_waitcnt vmcnt(" #N ")"                                         \
               : "+v"(X[0]), "+v"(X[1]), "+v"(X[2]), "+v"(X[3]),                 \
                 "+v"(X[4]), "+v"(X[5]), "+v"(X[6]), "+v"(X[7]))

#define MFMA_S(AV, S_)                                                           \
  do {                                                                           \
    _Pragma("unroll")                                                            \
    for (int mt_ = 0; mt_ < 4; ++mt_) {                                          \
      _Pragma("unroll")                                                          \
      for (int g_ = 0; g_ < 4; ++g_)                                             \
        acc[mt_][g_] = __builtin_amdgcn_mfma_f32_16x16x32_bf16(                  \
            (AV)[mt_], bF[g_][S_], acc[mt_][g_], 0, 0, 0);                       \
    }                                                                            \
  } while (0)

// K=128 half: 16 loads ping-ponged through 2 reg groups, 4 MFMA chunks.
// Counts remain correct with one carried (older) store outstanding: the first
// WAIT4(4) retires {store, u0}.
#define SELF_SEQ(ISS, PBASE)                                                     \
  do {                                                                           \
    short8 u0[4], u1[4];                                                         \
    ISS(u0, (PBASE));                                                            \
    ISS(u1, (PBASE) + 4096);                                                     \
    WAIT4(4, u0); MFMA_S(u0, 0); ISS(u0, (PBASE) + 8192);                        \
    WAIT4(4, u1); MFMA_S(u1, 1); ISS(u1, (PBASE) + 12288);                       \
    WAIT4(4, u0); MFMA_S(u0, 2);                                                 \
    WAIT4(0, u1); MFMA_S(u1, 3);                                                 \
  } while (0)

// One-time fence-free global barrier (prologue handoff only) -- proven.
__device__ __forceinline__ void grid_barrier(unsigned target) {
  asm volatile("s_waitcnt vmcnt(0)" ::: "memory");
  __syncthreads();
  if (threadIdx.x == 0) {
    unsigned long long old = __hip_atomic_fetch_add(&g_word, 1ull, __ATOMIC_RELAXED,
                                                    __HIP_MEMORY_SCOPE_AGENT);
    if ((unsigned)(old & 0xffffffffull) == NBLK - 1) {
      __hip_atomic_fetch_add(&g_word, (1ull << 32) - (unsigned long long)NBLK,
                             __ATOMIC_RELAXED, __HIP_MEMORY_SCOPE_AGENT);
    } else {
      while ((int)((unsigned)(__hip_atomic_load(&g_word, __ATOMIC_RELAXED,
                                                __HIP_MEMORY_SCOPE_AGENT) >> 32) - target) < 0)
        __builtin_amdgcn_s_sleep(2);
    }
  }
  __syncthreads();
}

extern "C" __global__ __launch_bounds__(NTHR, 2) void lstm_persistent(
    const float* __restrict__ x,
    const float* __restrict__ W0, const float* __restrict__ U0, const float* __restrict__ b0,
    const float* __restrict__ W1, const float* __restrict__ U1, const float* __restrict__ b1,
    const float* __restrict__ W2, const float* __restrict__ U2, const float* __restrict__ b2,
    float* __restrict__ out,
    int* __restrict__ flags,             // ws: +1024 glob flags (3x256B), +2048 cnt[3] (128B apart)
    unsigned short* __restrict__ hbufL,  // ws+4096: local rings [3][RL][slab]
    unsigned short* __restrict__ hbufR,  // after:   remote rings [2][rrm+1][slab]
    int big, int rrm)
{
  // LDS union: weight staging (prologue only) then Zp partials (steady).
  __shared__ __align__(16) char smem[512 * ZPAD * 4];   // 143360 B => 1 block/CU
  unsigned short (*Wl)[KPAD] = (unsigned short (*)[KPAD])smem;  // [64][1032]
  float (*Zp)[ZPAD] = (float (*)[ZPAD])smem;                    // [512][70]
  __shared__ float biasl[64];
  __shared__ unsigned hpk[NTHR];        // h relay: phase2 -> tail publish
  __shared__ int s_l, s_sl, s_bgo, s_go;
  __shared__ unsigned s_gen0;

  const int tid = threadIdx.x;

  // ---- XCD discovery + role claim (validated rounds 1-2) ----
  if (tid == 0) {
    s_gen0 = (unsigned)(__hip_atomic_load(&g_word, __ATOMIC_RELAXED,
                                          __HIP_MEMORY_SCOPE_AGENT) >> 32);
    unsigned xid;
    asm volatile("s_getreg_b32 %0, hwreg(HW_REG_XCC_ID)" : "=s"(xid));
    const int xcd = (int)(xid & 7u);
    unsigned r = __hip_atomic_fetch_add(&g_cnt[xcd], 1u, __ATOMIC_RELAXED,
                                        __HIP_MEMORY_SCOPE_AGENT);
    s_l = (xcd < 3) ? xcd : -1;
    s_sl = (int)(r & 31u);
    s_bgo = -1;
    s_go = -1;
  }
  __syncthreads();
  const int l = s_l;
  const int slice = s_sl;
  if (l < 0) { grid_barrier(s_gen0 + 1); return; }   // idle XCDs exit

  const float* Wsrc = (l == 0) ? W0 : (l == 1) ? W1 : W2;
  const float* Usrc = (l == 0) ? U0 : (l == 1) ? U1 : U2;
  const float* bsrc = (l == 0) ? b0 : (l == 1) ? b1 : b2;
  const int Kx = (l == 0) ? DD : HH;      // input-half K
  const int j0g = slice * 16;

  // slab layout: [32 slices][64 b][16 cols] -- producer writes contiguous 2KB.
  #define SLAB_L(LL, T_) (hbufL + (size_t)((LL) * RL + ((T_) & (RL - 1))) * SS)
  #define SLAB_R(BB_, T_) (hbufR + (size_t)((BB_) * (rrm + 1) + ((T_) & rrm)) * SS)

  int* fl_glob  = (int*)((char*)flags + 1024 + (size_t)l * 256);   // IC flags
  int* fl_gprev = (l > 0) ? (int*)((char*)flags + 1024 + (size_t)(l - 1) * 256) : fl_glob;
  int* fl_gnext = (l < 2) ? (int*)((char*)flags + 1024 + (size_t)(l + 1) * 256) : fl_glob;
  unsigned* cntp = (unsigned*)((char*)flags + 2048 + (size_t)l * 128);  // L2 arrival ctr

  // monotone base snapshot (no reset needed; robust across calls)
  unsigned cbase = 0;
  if (tid == 256) cbase = atom_rd(cntp);

  // ---- prologue: stage [W;U]^T slice as bf16 into LDS (64 gate cols) ----
  for (int q = 0; q < 8; ++q) {
    const int gcol = (q >> 1) * HH + j0g + (q & 1) * 8;
    for (int k = tid; k < Kx; k += NTHR) {
      const float* s = Wsrc + (size_t)k * GG + gcol;
      #pragma unroll
      for (int c = 0; c < 8; ++c) Wl[q * 8 + c][k] = (unsigned short)f2bf(s[c]);
    }
    for (int k = tid; k < HH; k += NTHR) {
      const float* s = Usrc + (size_t)k * GG + gcol;
      #pragma unroll
      for (int c = 0; c < 8; ++c) Wl[q * 8 + c][Kx + k] = (unsigned short)f2bf(s[c]);
    }
  }
  if (tid < 64) biasl[tid] = bsrc[(tid >> 4) * HH + j0g + (tid & 15)];

  // zero my slice of the t=-1 local slab (h0 = 0) with WT stores; glob flags
  { unsigned* z = (unsigned*)(SLAB_L(l, -1) + slice * 1024); stS(z + tid, 0u); }
  if (slice == 0 && tid < 32) stH(fl_glob + tid, 0u);
  __syncthreads();

  // ---- B fragments -> registers (64 VGPR/wave); LDS then freed for Zp ----
  const int lane = tid & 63;
  const int wv   = tid >> 6;
  const int quad = lane >> 4;
  const int m    = lane & 15;
  const int col  = m;
  const bool selfw = (wv >= 4);
  int kbase;
  if (l == 0) kbase = selfw ? 256 + 128 * (wv - 4) : 64 * wv;   // x-waves: K=64 each
  else        kbase = selfw ? 512 + 128 * (wv - 4) : 128 * wv;

  short8 bF[4][4];
  #pragma unroll
  for (int g = 0; g < 4; ++g)
    #pragma unroll
    for (int s = 0; s < 4; ++s)
      bF[g][s] = *(const short8*)&Wl[g * 16 + col][kbase + 32 * s + quad * 8];

  grid_barrier(s_gen0 + 1);   // single global handoff; steady state is dataflow

  // per-lane byte offsets inside a slab for A loads
  const size_t laneoff  = (size_t)(quad >> 1) * 2048 + (size_t)(quad & 1) * 16 + (size_t)m * 32;
  const size_t selfoff  = (size_t)(128 * (wv - 4)) * 128 + laneoff;   // valid when selfw
  const size_t belowoff = (size_t)(128 * wv) * 128 + laneoff;

  const int* pb = fl_gprev + (lane & 31);
  const int* pa = fl_gnext + (lane & 31);

  float cR[2] = {0.f, 0.f};   // c-state in registers: thread owns (b, 2 h-cols)
  int fbs = -1;               // cached below-flag (wave 0 lanes)
  int fas = -1;               // cached above-flag (ring guard, small mode only)

  for (int t = 0; t < TT; ++t) {
    f32x4 acc[4][4];
    #pragma unroll
    for (int a_ = 0; a_ < 4; ++a_)
      #pragma unroll
      for (int g_ = 0; g_ < 4; ++g_) acc[a_][g_] = (f32x4){0.f, 0.f, 0.f, 0.f};

    if (selfw) {
      // ---- THE critical path: L2-atomic arrival poll + L2 h_self loads ----
      // (no IC ops live on these waves => the vmcnt(0)s here are L2-cheap)
      if (tid == 256) {
        const unsigned tgt = cbase + 32u * (unsigned)t;
        for (int it = 0; it < POLL_CAP; ++it)
          if ((int)(atom_rd(cntp) - tgt) >= 0) break;
        ((volatile int*)&s_go)[0] = t;
      }
      { int sp = 0;
        while (((volatile int*)&s_go)[0] < t && sp < SPIN_CAP) ++sp; }
      INV();   // drop L1 so plain loads see the L2-dirty ring
      const char* pp0 = (const char*)SLAB_L(l, t - 1) + selfoff;
      SELF_SEQ(ISSUE4_A0, pp0);
    } else if (l > 0) {
      // ---- h_below half: IC flags cached off the period; IC/big-ring data --
      if (wv == 0) {
        const bool needb = __any(fbs < t + 1);
        const bool needa = (!big && l == 1) ? __any(fas < t - rrm) : false;
        if (needb || needa) {
          for (int it = 0; it < POLL_CAP; ++it) {
            fbs = ld_icc(pb);
            if (!big && l == 1) fas = ld_icc(pa);
            bool ok = (fbs >= t + 1);
            if (!big && l == 1) ok = ok && (fas >= t - rrm);
            if (__all(ok)) break;
            __builtin_amdgcn_s_sleep(1);
          }
        }
        ((volatile int*)&s_bgo)[0] = t;          // funnel: 1 IC poller per block
      } else {
        int sp = 0;
        while (((volatile int*)&s_bgo)[0] < t && sp < SPIN_CAP) ++sp;
      }
      const char* pp0 = (const char*)SLAB_R(l - 1, t) + belowoff;
      if (big) { SELF_SEQ(ISSUE4_A0, pp0); }      // write-once ring: cached loads
      else     { SELF_SEQ(ISSUE4_AH, pp0); }      // small ring: IC-direct
    } else {
      // ---- layer 0 x half; ring guard only needed in small mode ----
      if (!big && wv == 0) {
        if (__any(fas < t - rrm)) {
          for (int it = 0; it < POLL_CAP; ++it) {
            fas = ld_icc(pa);
            if (__all(fas >= t - rrm)) break;
            __builtin_amdgcn_s_sleep(1);
          }
        }
      }
      const float* pX[4];
      #pragma unroll
      for (int mt = 0; mt < 4; ++mt)
        pX[mt] = x + ((size_t)(16 * mt + m) * TT + t) * DD + wv * 64 + quad * 8;
      f4 xv0[8], xv1[8];
      ISSUE_X(xv0, 0, 16, pX);
      ISSUE_X(xv1, 128, 144, pX);
      WAIT8(8, xv0);     // retires {carried stH2, xv0} when a store is live
      { short8 a2[4] = {pack8(xv0[0], xv0[1]), pack8(xv0[2], xv0[3]),
                        pack8(xv0[4], xv0[5]), pack8(xv0[6], xv0[7])};
        MFMA_S(a2, 0); }
      WAIT8(0, xv1);
      { short8 a2[4] = {pack8(xv1[0], xv1[1]), pack8(xv1[2], xv1[3]),
                        pack8(xv1[4], xv1[5]), pack8(xv1[6], xv1[7])};
        MFMA_S(a2, 1); }
    }

    // ---- Zp partial write: C/D layout col=lane&15, row=quad*4+reg ----
    #pragma unroll
    for (int mt = 0; mt < 4; ++mt)
      #pragma unroll
      for (int g = 0; g < 4; ++g)
        #pragma unroll
        for (int rg = 0; rg < 4; ++rg)
          Zp[wv * 64 + 16 * mt + 4 * quad + rg][g * 16 + col] = acc[mt][g][rg];

    __syncthreads();   // barrier 1

    // IC publish: slab t-1's remote stores (issued in tail of t-1 by waves
    // 0-3) retired at each wave's first WAIT this step => sealed at barrier 1.
    if (tid == 0) stH(fl_glob + slice, (unsigned)t);

    // ---- phase 2: 8-partial reduce + gates; thread owns (b, 2 h-cols) ----
    {
      const int b_ = tid >> 3;
      const int hp = tid & 7;
      float zz[2][4];
      #pragma unroll
      for (int g = 0; g < 4; ++g) {
        zz[0][g] = biasl[g * 16 + 2 * hp];
        zz[1][g] = biasl[g * 16 + 2 * hp + 1];
      }
      #pragma unroll
      for (int w = 0; w < 8; ++w)
        #pragma unroll
        for (int g = 0; g < 4; ++g) {
          const float2 v = *(const float2*)&Zp[w * 64 + b_][g * 16 + 2 * hp];
          zz[0][g] += v.x; zz[1][g] += v.y;
        }
      float hh2[2], cc2[2];
      #pragma unroll
      for (int e = 0; e < 2; ++e) {
        const float gi = sigm(zz[e][0]), gf = sigm(zz[e][1]);
        const float gz = tanh_(zz[e][2]), go = sigm(zz[e][3]);
        const float cc = gf * cR[e] + gi * gz;
        cR[e] = cc; cc2[e] = cc;
        hh2[e] = go * tanh_(cc);
      }
      const unsigned pk = (unsigned)(unsigned short)f2bf(hh2[0]) |
                          ((unsigned)(unsigned short)f2bf(hh2[1]) << 16);
      hpk[tid] = pk;                                        // relay for remote
      unsigned* dL = (unsigned*)(SLAB_L(l, t) + slice * 1024);
      stS(dL + tid, pk);                                    // local WT only
      if (t == TT - 1) {
        const int oi = b_ * HH + j0g + 2 * hp;
        if (l == 0) {
          out[SS + oi] = hh2[0];      out[SS + oi + 1] = hh2[1];
          out[2 * SS + oi] = cc2[0];  out[2 * SS + oi + 1] = cc2[1];
        } else if (l == 1) {
          out[3 * SS + oi] = hh2[0];  out[3 * SS + oi + 1] = hh2[1];
          out[4 * SS + oi] = cc2[0];  out[4 * SS + oi + 1] = cc2[1];
        } else {
          out[oi] = hh2[0];           out[oi + 1] = hh2[1];
          out[5 * SS + oi] = hh2[0];  out[5 * SS + oi + 1] = hh2[1];
          out[6 * SS + oi] = cc2[0];  out[6 * SS + oi + 1] = cc2[1];
        }
      }
    }

    // drain local stS in every wave (L2 ack, cheap -- no IC ops outstanding
    // on any wave here) -> slab(t) certified in L2 at barrier 2
    asm volatile("s_waitcnt vmcnt(0)" ::: "memory");
    __syncthreads();   // barrier 2 (also protects Zp/hpk reuse)

    // local arrival FIRST (gates all 32 blocks' next self poll) ...
    if (tid == 0) atom_add1(cntp);
    // ... then the IC publish of slab t by waves 0-3 from the relay.
    // No drain here: the store is the oldest vmem op at next step's first
    // WAIT and retires there, overlapped with load latency.
    if (!selfw && l < 2) {
      u32x2 hv = *(const u32x2*)&hpk[2 * tid];
      unsigned* dR = (unsigned*)(SLAB_R(l, t) + slice * 1024) + 2 * tid;
      stH2(dR, hv);
    }
  }

  // final seal: drain everything (incl. slab TT-1 publish), then flag TT
  asm volatile("s_waitcnt vmcnt(0)" ::: "memory");
  __syncthreads();
  if (tid == 0) stH(fl_glob + slice, (unsigned)TT);

  #undef SLAB_L
  #undef SLAB_R
}

extern "C" void kernel_launch(void* const* d_in, const int* in_sizes, int n_in,
                              void* d_out, int out_size, void* d_ws, size_t ws_size,
                              hipStream_t stream) {
  const float* x  = (const float*)d_in[0];
  const float* W0 = (const float*)d_in[1];
  const float* U0 = (const float*)d_in[2];
  const float* b0 = (const float*)d_in[3];
  const float* W1 = (const float*)d_in[4];
  const float* U1 = (const float*)d_in[5];
  const float* b1 = (const float*)d_in[6];
  const float* W2 = (const float*)d_in[7];
  const float* U2 = (const float*)d_in[8];
  const float* b2 = (const float*)d_in[9];
  float* out = (float*)d_out;
  int* flags = (int*)d_ws;
  unsigned short* hbufL = (unsigned short*)((char*)d_ws + 4096);
  unsigned short* hbufR = hbufL + (size_t)3 * RL * SS;

  // remote rings: full-T (write-once => cached consumer loads) if workspace
  // fits, else 16-slot IC-direct fallback.
  const size_t need_big = 4096 + (size_t)3 * RL * SS * 2 + (size_t)2 * TT * SS * 2;
  int big = (ws_size >= need_big) ? 1 : 0;
  int rrm = big ? (TT - 1) : 15;

  void* args[] = {(void*)&x,
                  (void*)&W0, (void*)&U0, (void*)&b0,
                  (void*)&W1, (void*)&U1, (void*)&b1,
                  (void*)&W2, (void*)&U2, (void*)&b2,
                  (void*)&out, (void*)&flags, (void*)&hbufL, (void*)&hbufR,
                  (void*)&big, (void*)&rrm};
  hipLaunchCooperativeKernel((void*)lstm_persistent, dim3(NBLK), dim3(NTHR),
                             args, 0, stream);
}

// Round 5
// 2789.363 us; speedup vs baseline: 1.0186x; 1.0186x over previous
//
#include <hip/hip_runtime.h>
#include <hip/hip_bf16.h>

// ---------------------------------------------------------------------------
// XCD-local persistent LSTM, round 5 = round-4 skeleton (2841us, passed) + ONE
// change: TRANSPOSED Zp layout to eliminate ~2050cy/step of LDS bank-conflict
// serialization (SQ_LDS_BANK_CONFLICT 1.007e8, constant across rounds 2-4).
//  - Zpt[64 gate-cols][516] f32 (pad 516 => 516%32=4):
//      writes: acc[mt][g] lands as ONE ds_write_b128 (rg contiguous in the
//              minor dim); bank starts 4*(m+quad)%32 partition all 32 banks
//              evenly -> minimum-cycle, conflict-free.  16 insts/thread
//              (was 64 scalar b32 with partial conflicts).
//      reads:  phase-2 b32 at bank (8hp+bb)%32 -> exact 2-way = free.
//              (old layout: even-banks-only => ~4-way on 256 b64/step).
//  - LDS union stays byte-exact: [64][516] f32 == [64][1032] short == 132096B
//    (weight staging unchanged).  132KB > 80KB keeps 1 block/CU pigeonhole.
//  - NOTHING else changed: protocol, vmcnt counts, publish, polls identical
//    to round 4.  (Round-3 lesson: one axis per round; prefer edits that
//    cannot perturb the sync structure.)
// ---------------------------------------------------------------------------

#define BB 64
#define TT 512
#define DD 256
#define HH 512
#define GG 2048
#define SS (BB * HH)          // shorts per h slab (64 KB)
#define NBLK 256
#define NTHR 512
#define RL 8                  // local ring slots (L2-resident)
#define KPAD 1032
#define ZLD 516               // transposed-Zp leading dim (f32 words)
#define POLL_CAP 20000
#define SPIN_CAP (1 << 20)

using short8 = __attribute__((ext_vector_type(8))) short;
using f32x4  = __attribute__((ext_vector_type(4))) float;
using f4     = f32x4;
using u32x2  = __attribute__((ext_vector_type(2))) unsigned;

__device__ unsigned long long g_word = 0;
__device__ unsigned g_cnt[8] = {};

__device__ __forceinline__ short f2bf(float f) {
  unsigned u = __builtin_bit_cast(unsigned, f);
  u = (u + 0x7fffu + ((u >> 16) & 1u)) >> 16;   // RNE
  return (short)u;
}
__device__ __forceinline__ float sigm(float x)  { return 1.f / (1.f + __expf(-x)); }
__device__ __forceinline__ float tanh_(float x) { return 2.f / (1.f + __expf(-2.f * x)) - 1.f; }

__device__ __forceinline__ short8 pack8(const f4& lo, const f4& hi) {
  return (short8){f2bf(lo[0]), f2bf(lo[1]), f2bf(lo[2]), f2bf(lo[3]),
                  f2bf(hi[0]), f2bf(hi[1]), f2bf(hi[2]), f2bf(hi[3])};
}

// device-coherent (IC) stores -- cross-XCD protocol (proven)
__device__ __forceinline__ void stH(void* p, unsigned v) {
  asm volatile("global_store_dword %0, %1, off sc0 sc1" :: "v"(p), "v"(v) : "memory");
}
__device__ __forceinline__ void stH2(void* p, u32x2 v) {
  asm volatile("global_store_dwordx2 %0, %1, off sc0 sc1" :: "v"(p), "v"(v) : "memory");
}
// write-through store -- lands in the XCD L2 (proven round 2)
__device__ __forceinline__ void stS(void* p, unsigned v) {
  asm volatile("global_store_dword %0, %1, off sc0" :: "v"(p), "v"(v) : "memory");
}
// device-coherent poll load (IC)
__device__ __forceinline__ int ld_icc(const int* p) {
  int v;
  asm volatile("global_load_dword %0, %1, off sc0 sc1\n\ts_waitcnt vmcnt(0)"
               : "=v"(v) : "v"(p) : "memory");
  return v;
}
// L2 atomic read (return-old of +0) -- executes in L2, L1-immune (proven)
__device__ __forceinline__ unsigned atom_rd(unsigned* p) {
  unsigned old, zero = 0;
  asm volatile("global_atomic_add %0, %1, %2, off sc0\n\ts_waitcnt vmcnt(0)"
               : "=v"(old) : "v"(p), "v"(zero) : "memory");
  return old;
}
// L2 atomic add (fire-and-forget)
__device__ __forceinline__ void atom_add1(unsigned* p) {
  unsigned one = 1;
  asm volatile("global_atomic_add %0, %1, off" :: "v"(p), "v"(one) : "memory");
}
// L1 invalidate (acquire) -- proven round 2
#define INV() asm volatile("buffer_inv sc0\n\ts_waitcnt vmcnt(0)" ::: "memory")

// A loads: 4 M-tiles from one per-lane pointer (+512B per tile)
#define ISSUE4_A0(A, P)                                                        \
  asm volatile("global_load_dwordx4 %0, %4, off\n\t"                           \
               "global_load_dwordx4 %1, %4, off offset:512\n\t"                \
               "global_load_dwordx4 %2, %4, off offset:1024\n\t"               \
               "global_load_dwordx4 %3, %4, off offset:1536"                   \
               : "=&v"(A[0]), "=&v"(A[1]), "=&v"(A[2]), "=&v"(A[3]) : "v"(P))
#define ISSUE4_AH(A, P)                                                        \
  asm volatile("global_load_dwordx4 %0, %4, off sc0 sc1\n\t"                   \
               "global_load_dwordx4 %1, %4, off offset:512 sc0 sc1\n\t"        \
               "global_load_dwordx4 %2, %4, off offset:1024 sc0 sc1\n\t"       \
               "global_load_dwordx4 %3, %4, off offset:1536 sc0 sc1"           \
               : "=&v"(A[0]), "=&v"(A[1]), "=&v"(A[2]), "=&v"(A[3]) : "v"(P))

#define ISSUE_X(X, O0, O1, P)                                                    \
  asm volatile("global_load_dwordx4 %0, %8, off offset:" #O0 "\n\t"              \
               "global_load_dwordx4 %1, %8, off offset:" #O1 "\n\t"              \
               "global_load_dwordx4 %2, %9, off offset:" #O0 "\n\t"              \
               "global_load_dwordx4 %3, %9, off offset:" #O1 "\n\t"              \
               "global_load_dwordx4 %4, %10, off offset:" #O0 "\n\t"             \
               "global_load_dwordx4 %5, %10, off offset:" #O1 "\n\t"             \
               "global_load_dwordx4 %6, %11, off offset:" #O0 "\n\t"             \
               "global_load_dwordx4 %7, %11, off offset:" #O1                    \
               : "=&v"(X[0]), "=&v"(X[1]), "=&v"(X[2]), "=&v"(X[3]),             \
                 "=&v"(X[4]), "=&v"(X[5]), "=&v"(X[6]), "=&v"(X[7])              \
               : "v"(P[0]), "v"(P[1]), "v"(P[2]), "v"(P[3]))

#define WAIT4(N, A)                                                              \
  asm volatile("s_waitcnt vmcnt(" #N ")"                                         \
               : "+v"(A[0]), "+v"(A[1]), "+v"(A[2]), "+v"(A[3]))
#define WAIT8(N, X)                                                              \
  asm volatile("s_waitcnt vmcnt(" #N ")"                                         \
               : "+v"(X[0]), "+v"(X[1]), "+v"(X[2]), "+v"(X[3]),                 \
                 "+v"(X[4]), "+v"(X[5]), "+v"(X[6]), "+v"(X[7]))

#define MFMA_S(AV, S_)                                                           \
  do {                                                                           \
    _Pragma("unroll")                                                            \
    for (int mt_ = 0; mt_ < 4; ++mt_) {                                          \
      _Pragma("unroll")                                                          \
      for (int g_ = 0; g_ < 4; ++g_)                                             \
        acc[mt_][g_] = __builtin_amdgcn_mfma_f32_16x16x32_bf16(                  \
            (AV)[mt_], bF[g_][S_], acc[mt_][g_], 0, 0, 0);                       \
    }                                                                            \
  } while (0)

// K=128 half: 16 loads ping-ponged through 2 reg groups, 4 MFMA chunks.
// Counts remain correct with one carried (older) store outstanding.
#define SELF_SEQ(ISS, PBASE)                                                     \
  do {                                                                           \
    short8 u0[4], u1[4];                                                         \
    ISS(u0, (PBASE));                                                            \
    ISS(u1, (PBASE) + 4096);                                                     \
    WAIT4(4, u0); MFMA_S(u0, 0); ISS(u0, (PBASE) + 8192);                        \
    WAIT4(4, u1); MFMA_S(u1, 1); ISS(u1, (PBASE) + 12288);                       \
    WAIT4(4, u0); MFMA_S(u0, 2);                                                 \
    WAIT4(0, u1); MFMA_S(u1, 3);                                                 \
  } while (0)

// One-time fence-free global barrier (prologue handoff only) -- proven.
__device__ __forceinline__ void grid_barrier(unsigned target) {
  asm volatile("s_waitcnt vmcnt(0)" ::: "memory");
  __syncthreads();
  if (threadIdx.x == 0) {
    unsigned long long old = __hip_atomic_fetch_add(&g_word, 1ull, __ATOMIC_RELAXED,
                                                    __HIP_MEMORY_SCOPE_AGENT);
    if ((unsigned)(old & 0xffffffffull) == NBLK - 1) {
      __hip_atomic_fetch_add(&g_word, (1ull << 32) - (unsigned long long)NBLK,
                             __ATOMIC_RELAXED, __HIP_MEMORY_SCOPE_AGENT);
    } else {
      while ((int)((unsigned)(__hip_atomic_load(&g_word, __ATOMIC_RELAXED,
                                                __HIP_MEMORY_SCOPE_AGENT) >> 32) - target) < 0)
        __builtin_amdgcn_s_sleep(2);
    }
  }
  __syncthreads();
}

extern "C" __global__ __launch_bounds__(NTHR, 2) void lstm_persistent(
    const float* __restrict__ x,
    const float* __restrict__ W0, const float* __restrict__ U0, const float* __restrict__ b0,
    const float* __restrict__ W1, const float* __restrict__ U1, const float* __restrict__ b1,
    const float* __restrict__ W2, const float* __restrict__ U2, const float* __restrict__ b2,
    float* __restrict__ out,
    int* __restrict__ flags,             // ws: +1024 glob flags (3x256B), +2048 cnt[3] (128B apart)
    unsigned short* __restrict__ hbufL,  // ws+4096: local rings [3][RL][slab]
    unsigned short* __restrict__ hbufR,  // after:   remote rings [2][rrm+1][slab]
    int big, int rrm)
{
  // LDS union: weight staging (prologue only) then TRANSPOSED Zp partials.
  // [64][1032] shorts == [64][516] floats == 132096 B (>80KB => 1 block/CU).
  __shared__ __align__(16) char smem[64 * ZLD * 4];
  unsigned short (*Wl)[KPAD] = (unsigned short (*)[KPAD])smem;  // [64][1032]
  float (*Zpt)[ZLD] = (float (*)[ZLD])smem;                     // [64][516]
  __shared__ float biasl[64];
  __shared__ unsigned hpk[NTHR];        // h relay: phase2 -> tail publish
  __shared__ int s_l, s_sl, s_bgo, s_go;
  __shared__ unsigned s_gen0;

  const int tid = threadIdx.x;

  // ---- XCD discovery + role claim (validated rounds 1-4) ----
  if (tid == 0) {
    s_gen0 = (unsigned)(__hip_atomic_load(&g_word, __ATOMIC_RELAXED,
                                          __HIP_MEMORY_SCOPE_AGENT) >> 32);
    unsigned xid;
    asm volatile("s_getreg_b32 %0, hwreg(HW_REG_XCC_ID)" : "=s"(xid));
    const int xcd = (int)(xid & 7u);
    unsigned r = __hip_atomic_fetch_add(&g_cnt[xcd], 1u, __ATOMIC_RELAXED,
                                        __HIP_MEMORY_SCOPE_AGENT);
    s_l = (xcd < 3) ? xcd : -1;
    s_sl = (int)(r & 31u);
    s_bgo = -1;
    s_go = -1;
  }
  __syncthreads();
  const int l = s_l;
  const int slice = s_sl;
  if (l < 0) { grid_barrier(s_gen0 + 1); return; }   // idle XCDs exit

  const float* Wsrc = (l == 0) ? W0 : (l == 1) ? W1 : W2;
  const float* Usrc = (l == 0) ? U0 : (l == 1) ? U1 : U2;
  const float* bsrc = (l == 0) ? b0 : (l == 1) ? b1 : b2;
  const int Kx = (l == 0) ? DD : HH;      // input-half K
  const int j0g = slice * 16;

  // slab layout: [32 slices][64 b][16 cols] -- producer writes contiguous 2KB.
  #define SLAB_L(LL, T_) (hbufL + (size_t)((LL) * RL + ((T_) & (RL - 1))) * SS)
  #define SLAB_R(BB_, T_) (hbufR + (size_t)((BB_) * (rrm + 1) + ((T_) & rrm)) * SS)

  int* fl_glob  = (int*)((char*)flags + 1024 + (size_t)l * 256);   // IC flags
  int* fl_gprev = (l > 0) ? (int*)((char*)flags + 1024 + (size_t)(l - 1) * 256) : fl_glob;
  int* fl_gnext = (l < 2) ? (int*)((char*)flags + 1024 + (size_t)(l + 1) * 256) : fl_glob;
  unsigned* cntp = (unsigned*)((char*)flags + 2048 + (size_t)l * 128);  // L2 arrival ctr

  // monotone base snapshot (no reset needed; robust across calls)
  unsigned cbase = 0;
  if (tid == 256) cbase = atom_rd(cntp);

  // ---- prologue: stage [W;U]^T slice as bf16 into LDS (64 gate cols) ----
  for (int q = 0; q < 8; ++q) {
    const int gcol = (q >> 1) * HH + j0g + (q & 1) * 8;
    for (int k = tid; k < Kx; k += NTHR) {
      const float* s = Wsrc + (size_t)k * GG + gcol;
      #pragma unroll
      for (int c = 0; c < 8; ++c) Wl[q * 8 + c][k] = (unsigned short)f2bf(s[c]);
    }
    for (int k = tid; k < HH; k += NTHR) {
      const float* s = Usrc + (size_t)k * GG + gcol;
      #pragma unroll
      for (int c = 0; c < 8; ++c) Wl[q * 8 + c][Kx + k] = (unsigned short)f2bf(s[c]);
    }
  }
  if (tid < 64) biasl[tid] = bsrc[(tid >> 4) * HH + j0g + (tid & 15)];

  // zero my slice of the t=-1 local slab (h0 = 0) with WT stores; glob flags
  { unsigned* z = (unsigned*)(SLAB_L(l, -1) + slice * 1024); stS(z + tid, 0u); }
  if (slice == 0 && tid < 32) stH(fl_glob + tid, 0u);
  __syncthreads();

  // ---- B fragments -> registers (64 VGPR/wave); LDS then freed for Zpt ----
  const int lane = tid & 63;
  const int wv   = tid >> 6;
  const int quad = lane >> 4;
  const int m    = lane & 15;
  const int col  = m;
  const bool selfw = (wv >= 4);
  int kbase;
  if (l == 0) kbase = selfw ? 256 + 128 * (wv - 4) : 64 * wv;   // x-waves: K=64 each
  else        kbase = selfw ? 512 + 128 * (wv - 4) : 128 * wv;

  short8 bF[4][4];
  #pragma unroll
  for (int g = 0; g < 4; ++g)
    #pragma unroll
    for (int s = 0; s < 4; ++s)
      bF[g][s] = *(const short8*)&Wl[g * 16 + col][kbase + 32 * s + quad * 8];

  grid_barrier(s_gen0 + 1);   // single global handoff; steady state is dataflow

  // per-lane byte offsets inside a slab for A loads
  const size_t laneoff  = (size_t)(quad >> 1) * 2048 + (size_t)(quad & 1) * 16 + (size_t)m * 32;
  const size_t selfoff  = (size_t)(128 * (wv - 4)) * 128 + laneoff;   // valid when selfw
  const size_t belowoff = (size_t)(128 * wv) * 128 + laneoff;

  const int* pb = fl_gprev + (lane & 31);
  const int* pa = fl_gnext + (lane & 31);

  float cR[2] = {0.f, 0.f};   // c-state in registers: thread owns (b, 2 h-cols)
  int fbs = -1;               // cached below-flag (wave 0 lanes)
  int fas = -1;               // cached above-flag (ring guard, small mode only)

  for (int t = 0; t < TT; ++t) {
    f32x4 acc[4][4];
    #pragma unroll
    for (int a_ = 0; a_ < 4; ++a_)
      #pragma unroll
      for (int g_ = 0; g_ < 4; ++g_) acc[a_][g_] = (f32x4){0.f, 0.f, 0.f, 0.f};

    if (selfw) {
      // ---- THE critical path: L2-atomic arrival poll + L2 h_self loads ----
      if (tid == 256) {
        const unsigned tgt = cbase + 32u * (unsigned)t;
        for (int it = 0; it < POLL_CAP; ++it)
          if ((int)(atom_rd(cntp) - tgt) >= 0) break;
        ((volatile int*)&s_go)[0] = t;
      }
      { int sp = 0;
        while (((volatile int*)&s_go)[0] < t && sp < SPIN_CAP) ++sp; }
      INV();   // drop L1 so plain loads see the L2-dirty ring
      const char* pp0 = (const char*)SLAB_L(l, t - 1) + selfoff;
      SELF_SEQ(ISSUE4_A0, pp0);
    } else if (l > 0) {
      // ---- h_below half: IC flags cached off the period; IC/big-ring data --
      if (wv == 0) {
        const bool needb = __any(fbs < t + 1);
        const bool needa = (!big && l == 1) ? __any(fas < t - rrm) : false;
        if (needb || needa) {
          for (int it = 0; it < POLL_CAP; ++it) {
            fbs = ld_icc(pb);
            if (!big && l == 1) fas = ld_icc(pa);
            bool ok = (fbs >= t + 1);
            if (!big && l == 1) ok = ok && (fas >= t - rrm);
            if (__all(ok)) break;
            __builtin_amdgcn_s_sleep(1);
          }
        }
        ((volatile int*)&s_bgo)[0] = t;          // funnel: 1 IC poller per block
      } else {
        int sp = 0;
        while (((volatile int*)&s_bgo)[0] < t && sp < SPIN_CAP) ++sp;
      }
      const char* pp0 = (const char*)SLAB_R(l - 1, t) + belowoff;
      if (big) { SELF_SEQ(ISSUE4_A0, pp0); }      // write-once ring: cached loads
      else     { SELF_SEQ(ISSUE4_AH, pp0); }      // small ring: IC-direct
    } else {
      // ---- layer 0 x half; ring guard only needed in small mode ----
      if (!big && wv == 0) {
        if (__any(fas < t - rrm)) {
          for (int it = 0; it < POLL_CAP; ++it) {
            fas = ld_icc(pa);
            if (__all(fas >= t - rrm)) break;
            __builtin_amdgcn_s_sleep(1);
          }
        }
      }
      const float* pX[4];
      #pragma unroll
      for (int mt = 0; mt < 4; ++mt)
        pX[mt] = x + ((size_t)(16 * mt + m) * TT + t) * DD + wv * 64 + quad * 8;
      f4 xv0[8], xv1[8];
      ISSUE_X(xv0, 0, 16, pX);
      ISSUE_X(xv1, 128, 144, pX);
      WAIT8(8, xv0);     // retires {carried stH2, xv0} when a store is live
      { short8 a2[4] = {pack8(xv0[0], xv0[1]), pack8(xv0[2], xv0[3]),
                        pack8(xv0[4], xv0[5]), pack8(xv0[6], xv0[7])};
        MFMA_S(a2, 0); }
      WAIT8(0, xv1);
      { short8 a2[4] = {pack8(xv1[0], xv1[1]), pack8(xv1[2], xv1[3]),
                        pack8(xv1[4], xv1[5]), pack8(xv1[6], xv1[7])};
        MFMA_S(a2, 1); }
    }

    // ---- Zpt partial write (TRANSPOSED): one ds_write_b128 per (mt,g) ----
    // C/D layout col=lane&15, row=quad*4+reg; rg is contiguous in minor dim.
    #pragma unroll
    for (int mt = 0; mt < 4; ++mt)
      #pragma unroll
      for (int g = 0; g < 4; ++g)
        *(f32x4*)&Zpt[g * 16 + col][wv * 64 + 16 * mt + 4 * quad] = acc[mt][g];

    __syncthreads();   // barrier 1

    // IC publish: slab t-1's remote stores (issued in tail of t-1 by waves
    // 0-3) retired at each wave's first WAIT this step => sealed at barrier 1.
    if (tid == 0) stH(fl_glob + slice, (unsigned)t);

    // ---- phase 2: 8-partial reduce + gates; thread owns (b, 2 h-cols) ----
    {
      const int b_ = tid >> 3;
      const int hp = tid & 7;
      float zz[2][4];
      #pragma unroll
      for (int g = 0; g < 4; ++g) {
        zz[0][g] = biasl[g * 16 + 2 * hp];
        zz[1][g] = biasl[g * 16 + 2 * hp + 1];
      }
      #pragma unroll
      for (int w = 0; w < 8; ++w)
        #pragma unroll
        for (int g = 0; g < 4; ++g) {
          zz[0][g] += Zpt[g * 16 + 2 * hp    ][w * 64 + b_];
          zz[1][g] += Zpt[g * 16 + 2 * hp + 1][w * 64 + b_];
        }
      float hh2[2], cc2[2];
      #pragma unroll
      for (int e = 0; e < 2; ++e) {
        const float gi = sigm(zz[e][0]), gf = sigm(zz[e][1]);
        const float gz = tanh_(zz[e][2]), go = sigm(zz[e][3]);
        const float cc = gf * cR[e] + gi * gz;
        cR[e] = cc; cc2[e] = cc;
        hh2[e] = go * tanh_(cc);
      }
      const unsigned pk = (unsigned)(unsigned short)f2bf(hh2[0]) |
                          ((unsigned)(unsigned short)f2bf(hh2[1]) << 16);
      hpk[tid] = pk;                                        // relay for remote
      unsigned* dL = (unsigned*)(SLAB_L(l, t) + slice * 1024);
      stS(dL + tid, pk);                                    // local WT only
      if (t == TT - 1) {
        const int oi = b_ * HH + j0g + 2 * hp;
        if (l == 0) {
          out[SS + oi] = hh2[0];      out[SS + oi + 1] = hh2[1];
          out[2 * SS + oi] = cc2[0];  out[2 * SS + oi + 1] = cc2[1];
        } else if (l == 1) {
          out[3 * SS + oi] = hh2[0];  out[3 * SS + oi + 1] = hh2[1];
          out[4 * SS + oi] = cc2[0];  out[4 * SS + oi + 1] = cc2[1];
        } else {
          out[oi] = hh2[0];           out[oi + 1] = hh2[1];
          out[5 * SS + oi] = hh2[0];  out[5 * SS + oi + 1] = hh2[1];
          out[6 * SS + oi] = cc2[0];  out[6 * SS + oi + 1] = cc2[1];
        }
      }
    }

    // drain local stS in every wave (L2 ack, cheap) -> slab(t) certified
    asm volatile("s_waitcnt vmcnt(0)" ::: "memory");
    __syncthreads();   // barrier 2 (also protects Zpt/hpk reuse)

    // local arrival FIRST (gates all 32 blocks' next self poll) ...
    if (tid == 0) atom_add1(cntp);
    // ... then the IC publish of slab t by waves 0-3 from the relay.
    // No drain here: the store retires at next step's first WAIT, overlapped.
    if (!selfw && l < 2) {
      u32x2 hv = *(const u32x2*)&hpk[2 * tid];
      unsigned* dR = (unsigned*)(SLAB_R(l, t) + slice * 1024) + 2 * tid;
      stH2(dR, hv);
    }
  }

  // final seal: drain everything (incl. slab TT-1 publish), then flag TT
  asm volatile("s_waitcnt vmcnt(0)" ::: "memory");
  __syncthreads();
  if (tid == 0) stH(fl_glob + slice, (unsigned)TT);

  #undef SLAB_L
  #undef SLAB_R
}

extern "C" void kernel_launch(void* const* d_in, const int* in_sizes, int n_in,
                              void* d_out, int out_size, void* d_ws, size_t ws_size,
                              hipStream_t stream) {
  const float* x  = (const float*)d_in[0];
  const float* W0 = (const float*)d_in[1];
  const float* U0 = (const float*)d_in[2];
  const float* b0 = (const float*)d_in[3];
  const float* W1 = (const float*)d_in[4];
  const float* U1 = (const float*)d_in[5];
  const float* b1 = (const float*)d_in[6];
  const float* W2 = (const float*)d_in[7];
  const float* U2 = (const float*)d_in[8];
  const float* b2 = (const float*)d_in[9];
  float* out = (float*)d_out;
  int* flags = (int*)d_ws;
  unsigned short* hbufL = (unsigned short*)((char*)d_ws + 4096);
  unsigned short* hbufR = hbufL + (size_t)3 * RL * SS;

  // remote rings: full-T (write-once => cached consumer loads) if workspace
  // fits, else 16-slot IC-direct fallback.
  const size_t need_big = 4096 + (size_t)3 * RL * SS * 2 + (size_t)2 * TT * SS * 2;
  int big = (ws_size >= need_big) ? 1 : 0;
  int rrm = big ? (TT - 1) : 15;

  void* args[] = {(void*)&x,
                  (void*)&W0, (void*)&U0, (void*)&b0,
                  (void*)&W1, (void*)&U1, (void*)&b1,
                  (void*)&W2, (void*)&U2, (void*)&b2,
                  (void*)&out, (void*)&flags, (void*)&hbufL, (void*)&hbufR,
                  (void*)&big, (void*)&rrm};
  hipLaunchCooperativeKernel((void*)lstm_persistent, dim3(NBLK), dim3(NTHR),
                             args, 0, stream);
}